// Round 3
// baseline (115.731 us; speedup 1.0000x reference)
//
#include <hip/hip_runtime.h>
#include <stdint.h>
#include <math.h>

#define B_ 32
#define S_ 512
#define H_ 768
#define V_ 30522
#define M_ (B_*S_)   // 16384
#define N1_ 512

typedef __attribute__((ext_vector_type(8))) short bf16x8;
typedef __attribute__((ext_vector_type(4))) float f32x4;

__device__ __forceinline__ float bf2f(unsigned short u){
  union { unsigned int u; float f; } c; c.u = ((unsigned int)u)<<16; return c.f;
}
__device__ __forceinline__ unsigned short f2bf(float f){
  union { float f; unsigned int u; } c; c.f=f;
  unsigned int u = c.u + 0x7FFFu + ((c.u>>16)&1u);
  return (unsigned short)(u>>16);
}
__device__ __forceinline__ bool tbl_get(const void* t, int id, int flag){
  if(flag==1) return ((const int*)t)[id]!=0;
  if(flag==2) return ((const unsigned int*)t)[id]!=0u;   // f32 stored 0.0/1.0
  return ((const unsigned char*)t)[id]!=0;
}
__device__ __forceinline__ void gload_lds16(const void* g, void* l){
  __builtin_amdgcn_global_load_lds(
    (const __attribute__((address_space(1))) void*)g,
    (__attribute__((address_space(3))) void*)l, 16, 0, 0);
}

// ---- K0: detect in_table layout + per-row mask (0/1 f32) ----
__global__ __launch_bounds__(256) void k_detect_mask(const void* __restrict__ in_table,
  const int* __restrict__ ids, float* __restrict__ maskf){
  __shared__ int sflag;
  if(threadIdx.x==0){
    const int* pi = (const int*)in_table;
    bool all01=true, allf=true;
    for(int i=0;i<64;i++){
      int v = pi[i];
      if(v!=0 && v!=1) all01=false;
      unsigned int u=(unsigned int)v;
      if(u!=0u && u!=0x3F800000u) allf=false;
    }
    sflag = all01 ? 1 : (allf ? 2 : 0);
  }
  __syncthreads();
  const int flag = sflag;
  const int base = blockIdx.x*512;
  for(int i=threadIdx.x; i<512; i+=256){
    const int m = base + i;
    const bool mk = ((m & (S_-1)) != 0) && tbl_get(in_table, ids[m], flag);
    maskf[m] = mk ? 1.f : 0.f;
  }
}

// ---- K0b: deterministic compaction scan (single block) ----
__global__ __launch_bounds__(256) void k_scan(const float* __restrict__ maskf,
  int* __restrict__ perm, int* __restrict__ start, int* __restrict__ ncp){
  __shared__ int cnt[256];
  __shared__ int off[257];
  const int t = threadIdx.x;
  int c = 0;
  #pragma unroll 4
  for(int i=0;i<64;i++) c += (maskf[t*64+i] > 0.5f) ? 1 : 0;
  cnt[t] = c; __syncthreads();
  if(t==0){
    int r=0;
    for(int i=0;i<256;i++){ off[i]=r; r+=cnt[i]; }
    off[256]=r;
  }
  __syncthreads();
  if((t&7)==0) start[t>>3] = off[t];
  if(t==0){ start[32]=off[256]; *ncp=off[256]; }
  int base = off[t];
  for(int i=0;i<64;i++){
    const int m = t*64+i;
    if(maskf[m] > 0.5f) perm[base++] = m;
  }
}

// ---- K1: convert weights to bf16 (pad attention mats 100->128) ----
__global__ __launch_bounds__(256) void k_prepw(
  const float* __restrict__ W1, const float* __restrict__ W2,
  const float* __restrict__ Wa1, const float* __restrict__ Wa2, const float* __restrict__ ba1,
  unsigned short* __restrict__ W1bf, unsigned short* __restrict__ W2bf,
  unsigned short* __restrict__ Wa1bf, float* __restrict__ Wa2p, float* __restrict__ ba1p){
  const int g = blockIdx.x*256 + threadIdx.x, st = gridDim.x*256;
  for(int i=g;i<512*H_;i+=st) W1bf[i]=f2bf(W1[i]);
  for(int i=g;i<H_*512;i+=st) W2bf[i]=f2bf(W2[i]);
  for(int i=g;i<128*H_;i+=st) Wa1bf[i] = (i<100*H_)? f2bf(Wa1[i]) : (unsigned short)0;
  if(g < 128){ Wa2p[g] = (g<100)? Wa2[g] : 0.f; ba1p[g] = (g<100)? ba1[g] : 0.f; }
}

// ---- K2: gather compacted rows table[ids[perm[j]]] -> bf16 A [NC,768] ----
__global__ __launch_bounds__(256) void k_gather(const float* __restrict__ table,
  const int* __restrict__ ids, const int* __restrict__ perm, const int* __restrict__ ncp,
  unsigned short* __restrict__ A){
  const int NC = *ncp;
  const int t = threadIdx.x;
  for(int j = blockIdx.x; j < NC; j += gridDim.x){
    const int id = ids[perm[j]];
    if(t < 192){
      const float4 v = *(const float4*)(table + (size_t)id*H_ + (t<<2));
      ushort4 o; o.x=f2bf(v.x); o.y=f2bf(v.y); o.z=f2bf(v.z); o.w=f2bf(v.w);
      *(ushort4*)(A + (size_t)j*H_ + (t<<2)) = o;
    }
  }
}

// ---- MFMA GEMM over compacted rows: C = relu(A . Bw^T + bias) ----
// 128x128 tile, BK=32, 4 waves (2x2), 4x4 16x16x32 fragments/wave.
// LDS linear (global_load_lds); source slot inverse-swizzled, same swizzle on ds_read.
template<int KTOT, int NTOT>
__global__ __launch_bounds__(256) void k_gemm(
  const unsigned short* __restrict__ A, const unsigned short* __restrict__ Bw,
  const float* __restrict__ bias, const int* __restrict__ ncp,
  unsigned short* __restrict__ C)
{
  const int NC = *ncp;
  const int m0 = blockIdx.x << 7;
  if(m0 >= NC) return;
  __shared__ __align__(16) unsigned short As[128*32];
  __shared__ __align__(16) unsigned short Bs[128*32];
  const int tid = threadIdx.x;
  const int lane = tid & 63;
  const int wave = tid >> 6;
  const int wr = wave >> 1, wc = wave & 1;
  const int n0 = blockIdx.y << 7;

  const int f0 = tid, f1 = 256 + tid;
  const int r0 = f0 >> 2, s0 = ((f0 & 3) ^ ((f0 >> 3) & 3)) << 3;
  const int r1 = f1 >> 2, s1 = ((f1 & 3) ^ ((f1 >> 3) & 3)) << 3;
  const unsigned short* ga0 = A + (size_t)(m0 + r0)*KTOT + s0;
  const unsigned short* ga1 = A + (size_t)(m0 + r1)*KTOT + s1;
  const unsigned short* gb0 = Bw + (size_t)(n0 + r0)*KTOT + s0;
  const unsigned short* gb1 = Bw + (size_t)(n0 + r1)*KTOT + s1;
  unsigned short* la0 = As + (wave<<9);
  unsigned short* la1 = As + 2048 + (wave<<9);
  unsigned short* lb0 = Bs + (wave<<9);
  unsigned short* lb1 = Bs + 2048 + (wave<<9);

  f32x4 acc[4][4] = {};
  const int arow = (wr<<6) + (lane & 15);
  const int brow = (wc<<6) + (lane & 15);
  const int sl   = (((lane>>4) ^ ((lane>>1)&3)) << 3);

  for(int k0 = 0; k0 < KTOT; k0 += 32){
    gload_lds16(ga0 + k0, la0);
    gload_lds16(ga1 + k0, la1);
    gload_lds16(gb0 + k0, lb0);
    gload_lds16(gb1 + k0, lb1);
    __syncthreads();
    bf16x8 a[4], b[4];
    #pragma unroll
    for(int m=0;m<4;m++) a[m] = *(const bf16x8*)(As + (arow + (m<<4))*32 + sl);
    #pragma unroll
    for(int n=0;n<4;n++) b[n] = *(const bf16x8*)(Bs + (brow + (n<<4))*32 + sl);
    #pragma unroll
    for(int m=0;m<4;m++)
      #pragma unroll
      for(int n=0;n<4;n++)
        acc[m][n] = __builtin_amdgcn_mfma_f32_16x16x32_bf16(a[m], b[n], acc[m][n], 0,0,0);
    __syncthreads();
  }

  const int crow0 = (lane>>4) << 2;
  const int ccol  = lane & 15;
  float bia[4];
  #pragma unroll
  for(int n=0;n<4;n++) bia[n] = bias[n0 + (wc<<6) + (n<<4) + ccol];
  #pragma unroll
  for(int m=0;m<4;m++){
    const int gr0 = m0 + (wr<<6) + (m<<4) + crow0;
    #pragma unroll
    for(int j=0;j<4;j++){
      const size_t rbase = (size_t)(gr0 + j) * NTOT;
      #pragma unroll
      for(int n=0;n<4;n++){
        float v = acc[m][n][j] + bia[n];
        v = fmaxf(v, 0.f);
        C[rbase + n0 + (wc<<6) + (n<<4) + ccol] = f2bf(v);
      }
    }
  }
}

// ---- K5: compacted scores, scattered to full score array via perm ----
__global__ __launch_bounds__(256) void k_score(
  const unsigned short* __restrict__ A, const unsigned short* __restrict__ Bw,
  const float* __restrict__ ba1p, const float* __restrict__ Wa2p, const float* __restrict__ ba2,
  const int* __restrict__ perm, const int* __restrict__ ncp,
  float* __restrict__ scoresF)
{
  const int NC = *ncp;
  const int m0 = blockIdx.x << 7;
  if(m0 >= NC) return;
  __shared__ __align__(16) unsigned short As[128*32];
  __shared__ __align__(16) unsigned short Bs[128*32];
  __shared__ float sums[128][2];
  __shared__ int sperm[128];
  const int tid = threadIdx.x;
  const int lane = tid & 63;
  const int wave = tid >> 6;
  const int wr = wave >> 1, wc = wave & 1;
  if(tid < 128) sperm[tid] = perm[min(m0 + tid, M_-1)];

  const int f0 = tid, f1 = 256 + tid;
  const int r0 = f0 >> 2, s0 = ((f0 & 3) ^ ((f0 >> 3) & 3)) << 3;
  const int r1 = f1 >> 2, s1 = ((f1 & 3) ^ ((f1 >> 3) & 3)) << 3;
  const unsigned short* ga0 = A + (size_t)(m0 + r0)*H_ + s0;
  const unsigned short* ga1 = A + (size_t)(m0 + r1)*H_ + s1;
  const unsigned short* gb0 = Bw + (size_t)r0*H_ + s0;
  const unsigned short* gb1 = Bw + (size_t)r1*H_ + s1;
  unsigned short* la0 = As + (wave<<9);
  unsigned short* la1 = As + 2048 + (wave<<9);
  unsigned short* lb0 = Bs + (wave<<9);
  unsigned short* lb1 = Bs + 2048 + (wave<<9);

  f32x4 acc[4][4] = {};
  const int arow = (wr<<6) + (lane & 15);
  const int brow = (wc<<6) + (lane & 15);
  const int sl   = (((lane>>4) ^ ((lane>>1)&3)) << 3);

  for(int k0 = 0; k0 < H_; k0 += 32){
    gload_lds16(ga0 + k0, la0);
    gload_lds16(ga1 + k0, la1);
    gload_lds16(gb0 + k0, lb0);
    gload_lds16(gb1 + k0, lb1);
    __syncthreads();
    bf16x8 a[4], b[4];
    #pragma unroll
    for(int m=0;m<4;m++) a[m] = *(const bf16x8*)(As + (arow + (m<<4))*32 + sl);
    #pragma unroll
    for(int n=0;n<4;n++) b[n] = *(const bf16x8*)(Bs + (brow + (n<<4))*32 + sl);
    #pragma unroll
    for(int m=0;m<4;m++)
      #pragma unroll
      for(int n=0;n<4;n++)
        acc[m][n] = __builtin_amdgcn_mfma_f32_16x16x32_bf16(a[m], b[n], acc[m][n], 0,0,0);
    __syncthreads();
  }

  float psum[4][4] = {};
  #pragma unroll
  for(int n=0;n<4;n++){
    const int c = (wc<<6) + (n<<4) + (lane & 15);
    const float w2 = Wa2p[c], bb = ba1p[c];
    #pragma unroll
    for(int m=0;m<4;m++)
      #pragma unroll
      for(int j=0;j<4;j++)
        psum[m][j] = fmaf(tanhf(acc[m][n][j] + bb), w2, psum[m][j]);
  }
  #pragma unroll
  for(int msk=1; msk<16; msk<<=1)
    #pragma unroll
    for(int m=0;m<4;m++)
      #pragma unroll
      for(int j=0;j<4;j++)
        psum[m][j] += __shfl_xor(psum[m][j], msk, 64);
  if((lane & 15) == 0){
    #pragma unroll
    for(int m=0;m<4;m++)
      #pragma unroll
      for(int j=0;j<4;j++)
        sums[(wr<<6) + (m<<4) + ((lane>>4)<<2) + j][wc] = psum[m][j];
  }
  __syncthreads();
  if(tid < 128 && (m0 + tid) < NC)
    scoresF[sperm[tid]] = sums[tid][0] + sums[tid][1] + ba2[0];
}

// ---- K6: per-batch softmax; masked rows use constant score c0 ----
__global__ __launch_bounds__(256) void k_softmax(const float* __restrict__ scoresF,
  const float* __restrict__ maskf, const float* __restrict__ Wa2,
  const float* __restrict__ ba1, const float* __restrict__ ba2,
  float* __restrict__ attn){
  __shared__ float red[256];
  const int b = blockIdx.x, tid = threadIdx.x;
  // c0 = Wa2 . tanh(ba1) + ba2
  red[tid] = (tid < 100) ? Wa2[tid]*tanhf(ba1[tid]) : 0.f;
  __syncthreads();
  for(int st=128; st>0; st>>=1){ if(tid<st) red[tid]+=red[tid+st]; __syncthreads(); }
  const float c0 = red[0] + ba2[0];
  __syncthreads();
  const int m1 = b*S_ + tid, m2 = m1 + 256;
  const float s1 = (tid==0) ? -1e30f : (maskf[m1] > 0.5f ? scoresF[m1] : c0);
  const float s2 = (maskf[m2] > 0.5f ? scoresF[m2] : c0);
  red[tid] = fmaxf(s1, s2); __syncthreads();
  for(int st=128; st>0; st>>=1){ if(tid<st) red[tid]=fmaxf(red[tid], red[tid+st]); __syncthreads(); }
  const float mx = red[0]; __syncthreads();
  const float e1 = (tid==0) ? 0.f : __expf(s1-mx);
  const float e2 = __expf(s2-mx);
  red[tid] = e1+e2; __syncthreads();
  for(int st=128; st>0; st>>=1){ if(tid<st) red[tid]+=red[tid+st]; __syncthreads(); }
  const float inv = 1.f/red[0];
  attn[m1] = e1*inv;
  attn[m2] = e2*inv;
}

// ---- K7: partial[b][ch][h] over compacted segment of batch b ----
__global__ __launch_bounds__(256) void k_partial(const unsigned short* __restrict__ wh,
  const float* __restrict__ attn, const int* __restrict__ perm, const int* __restrict__ start,
  float* __restrict__ partial){
  const int b = blockIdx.x >> 3, ch = blockIdx.x & 7, tid = threadIdx.x;
  const int j0 = start[b] + (ch<<6);
  const int jend = min(start[b+1], j0 + 64);
  const int n = jend - j0;
  float* pp = partial + ((size_t)((b<<3)+ch))*H_;
  if(n <= 0){
    pp[tid] = 0.f; pp[tid+256] = 0.f; pp[tid+512] = 0.f;
    return;
  }
  __shared__ float wts[64];
  if(tid < 64) wts[tid] = (tid < n) ? attn[perm[j0+tid]] : 0.f;
  __syncthreads();
  float a0=0.f, a1=0.f, a2=0.f;
  for(int t=0;t<n;t++){
    const float wv = wts[t];
    const size_t base = ((size_t)(j0+t))*H_;
    a0 = fmaf(wv, bf2f(wh[base + tid      ]), a0);
    a1 = fmaf(wv, bf2f(wh[base + tid + 256]), a1);
    a2 = fmaf(wv, bf2f(wh[base + tid + 512]), a2);
  }
  pp[tid] = a0; pp[tid+256] = a1; pp[tid+512] = a2;
}

// ---- K8: predicts[b] = [hiddens[b,0,:], cls_k[b,:]] @ Wl^T + bl ----
__global__ __launch_bounds__(256) void k_predict(const float* __restrict__ hiddens,
  const float* __restrict__ partial, const float* __restrict__ Wl, const float* __restrict__ bl,
  float* __restrict__ out){
  __shared__ float ck[768];
  __shared__ float red[256];
  const int b = blockIdx.x, tid = threadIdx.x;
  #pragma unroll
  for(int r=0;r<3;r++){
    const int h = tid + (r<<8);
    float s=0.f;
    for(int c=0;c<8;c++) s += partial[((size_t)((b<<3)+c))*H_ + h];
    ck[h]=s;
  }
  __syncthreads();
  const float* hid = hiddens + (size_t)b * S_ * H_;
  for(int c=0;c<3;c++){
    float p=0.f;
    #pragma unroll
    for(int r=0;r<3;r++){
      const int h = tid + (r<<8);
      p = fmaf(hid[h], Wl[c*1536 + h], p);
      p = fmaf(ck[h],  Wl[c*1536 + 768 + h], p);
    }
    red[tid]=p; __syncthreads();
    for(int st=128; st>0; st>>=1){ if(tid<st) red[tid]+=red[tid+st]; __syncthreads(); }
    if(tid==0) out[b*3+c] = red[0] + bl[c];
    __syncthreads();
  }
}

extern "C" void kernel_launch(void* const* d_in, const int* in_sizes, int n_in,
                              void* d_out, int out_size, void* d_ws, size_t ws_size,
                              hipStream_t stream)
{
  const float* hiddens = (const float*)d_in[0];
  const int*   ids     = (const int*)d_in[1];
  const void*  in_tab  = d_in[2];
  const float* table   = (const float*)d_in[3];
  const float* W1      = (const float*)d_in[4];
  const float* b1      = (const float*)d_in[5];
  const float* W2      = (const float*)d_in[6];
  const float* b2      = (const float*)d_in[7];
  const float* Wa1     = (const float*)d_in[8];
  const float* ba1     = (const float*)d_in[9];
  const float* Wa2     = (const float*)d_in[10];
  const float* ba2     = (const float*)d_in[11];
  const float* Wl      = (const float*)d_in[12];
  const float* bl      = (const float*)d_in[13];
  float* out = (float*)d_out;

  char* w = (char*)d_ws;
  unsigned short* Abf   = (unsigned short*)w;                // 25165824 B (aliased by wh)
  unsigned short* wh    = Abf;                               // alias: A dead after mlp1
  unsigned short* x     = (unsigned short*)(w + 25165824);   // 16777216
  unsigned short* W1bf  = (unsigned short*)(w + 41943040);   // 786432
  unsigned short* W2bf  = (unsigned short*)(w + 42729472);   // 786432
  unsigned short* Wa1bf = (unsigned short*)(w + 43515904);   // 196608
  float* Wa2p    = (float*)(w + 43712512);                   // 512
  float* ba1p    = (float*)(w + 43713024);                   // 512
  float* maskf   = (float*)(w + 43713536);                   // 65536
  float* scoresF = (float*)(w + 43779072);                   // 65536
  float* attn    = (float*)(w + 43844608);                   // 65536
  float* partial = (float*)(w + 43910144);                   // 786432
  int*   perm    = (int*)  (w + 44696576);                   // 65536
  int*   startp  = (int*)  (w + 44762112);                   // 256 (33 used)
  int*   ncp     = (int*)  (w + 44762368);                   // 4

  hipLaunchKernelGGL(k_detect_mask, dim3(32),  dim3(256), 0, stream, in_tab, ids, maskf);
  hipLaunchKernelGGL(k_scan,   dim3(1),    dim3(256), 0, stream, maskf, perm, startp, ncp);
  hipLaunchKernelGGL(k_prepw,  dim3(768),  dim3(256), 0, stream, W1, W2, Wa1, Wa2, ba1, W1bf, W2bf, Wa1bf, Wa2p, ba1p);
  hipLaunchKernelGGL(k_gather, dim3(2048), dim3(256), 0, stream, table, ids, perm, ncp, Abf);
  hipLaunchKernelGGL((k_gemm<H_, N1_>), dim3(128, 4), dim3(256), 0, stream, Abf, W1bf, b1, ncp, x);
  hipLaunchKernelGGL((k_gemm<N1_, H_>), dim3(128, 6), dim3(256), 0, stream, x, W2bf, b2, ncp, wh);
  hipLaunchKernelGGL(k_score,   dim3(128), dim3(256), 0, stream, wh, Wa1bf, ba1p, Wa2p, ba2, perm, ncp, scoresF);
  hipLaunchKernelGGL(k_softmax, dim3(32),  dim3(256), 0, stream, scoresF, maskf, Wa2, ba1, ba2, attn);
  hipLaunchKernelGGL(k_partial, dim3(256), dim3(256), 0, stream, wh, attn, perm, startp, partial);
  hipLaunchKernelGGL(k_predict, dim3(32),  dim3(256), 0, stream, hiddens, partial, Wl, bl, out);
}

// Round 4
// 98.485 us; speedup vs baseline: 1.1751x; 1.1751x over previous
//
#include <hip/hip_runtime.h>
#include <stdint.h>
#include <math.h>

#define B_ 32
#define S_ 512
#define H_ 768
#define V_ 30522
#define M_ (B_*S_)   // 16384
#define N1_ 512

typedef __attribute__((ext_vector_type(8))) short bf16x8;
typedef __attribute__((ext_vector_type(4))) float f32x4;

__device__ __forceinline__ float bf2f(unsigned short u){
  union { unsigned int u; float f; } c; c.u = ((unsigned int)u)<<16; return c.f;
}
__device__ __forceinline__ unsigned short f2bf(float f){
  union { float f; unsigned int u; } c; c.f=f;
  unsigned int u = c.u + 0x7FFFu + ((c.u>>16)&1u);
  return (unsigned short)(u>>16);
}
__device__ __forceinline__ bool tbl_get(const void* t, int id, int flag){
  if(flag==1) return ((const int*)t)[id]!=0;
  if(flag==2) return ((const unsigned int*)t)[id]!=0u;   // f32 stored 0.0/1.0
  return ((const unsigned char*)t)[id]!=0;
}
__device__ __forceinline__ void gload_lds16(const void* g, void* l){
  __builtin_amdgcn_global_load_lds(
    (const __attribute__((address_space(1))) void*)g,
    (__attribute__((address_space(3))) void*)l, 16, 0, 0);
}

// ---- K0: per-batch mask + LDS prefix scan -> rank/perm/maskf/cnt. 32 blocks. ----
__global__ __launch_bounds__(256) void k_mask_scan(const void* __restrict__ in_table,
  const int* __restrict__ ids, float* __restrict__ maskf, int* __restrict__ rank,
  int* __restrict__ perm, int* __restrict__ cnt){
  __shared__ int sh[512];
  __shared__ int sflag;
  const int b = blockIdx.x, t = threadIdx.x;
  if(t < 64){
    const int v = ((const int*)in_table)[t];
    const unsigned int u = (unsigned int)v;
    const unsigned long long b01 = __ballot(v==0 || v==1);
    const unsigned long long bfl = __ballot(u==0u || u==0x3F800000u);
    if(t==0) sflag = (~b01==0ull) ? 1 : ((~bfl==0ull) ? 2 : 0);
  }
  __syncthreads();
  const int flag = sflag;
  const int m0 = b*S_ + t, m1 = m0 + 256;
  const int mk0 = ((t!=0) && tbl_get(in_table, ids[m0], flag)) ? 1 : 0;
  const int mk1 = tbl_get(in_table, ids[m1], flag) ? 1 : 0;
  sh[t] = mk0; sh[t+256] = mk1;
  __syncthreads();
  for(int off=1; off<512; off<<=1){
    const int a0 = (t >= off) ? sh[t-off] : 0;
    const int a1 = (t+256 >= off) ? sh[t+256-off] : 0;
    __syncthreads();
    sh[t] += a0; sh[t+256] += a1;
    __syncthreads();
  }
  const int r0 = sh[t] - mk0;
  const int r1 = sh[t+256] - mk1;
  maskf[m0] = mk0 ? 1.f : 0.f;
  maskf[m1] = mk1 ? 1.f : 0.f;
  rank[m0] = mk0 ? (b*S_ + r0) : -1;
  rank[m1] = mk1 ? (b*S_ + r1) : -1;
  if(mk0) perm[b*S_ + r0] = m0;
  if(mk1) perm[b*S_ + r1] = m1;
  if(t==0) cnt[b] = sh[511];
}

// ---- K1: convert weights to bf16 (pad attention mats 100->128) ----
__global__ __launch_bounds__(256) void k_prepw(
  const float* __restrict__ W1, const float* __restrict__ W2,
  const float* __restrict__ Wa1, const float* __restrict__ Wa2, const float* __restrict__ ba1,
  unsigned short* __restrict__ W1bf, unsigned short* __restrict__ W2bf,
  unsigned short* __restrict__ Wa1bf, float* __restrict__ Wa2p, float* __restrict__ ba1p){
  const int g = blockIdx.x*256 + threadIdx.x, st = gridDim.x*256;
  for(int i=g;i<512*H_;i+=st) W1bf[i]=f2bf(W1[i]);
  for(int i=g;i<H_*512;i+=st) W2bf[i]=f2bf(W2[i]);
  for(int i=g;i<128*H_;i+=st) Wa1bf[i] = (i<100*H_)? f2bf(Wa1[i]) : (unsigned short)0;
  if(g < 128){ Wa2p[g] = (g<100)? Wa2[g] : 0.f; ba1p[g] = (g<100)? ba1[g] : 0.f; }
}

// ---- K2: gather masked rows table[ids[m]] -> bf16 A at compacted slot rank[m] ----
__global__ __launch_bounds__(256) void k_gather(const float* __restrict__ table,
  const int* __restrict__ ids, const int* __restrict__ rank,
  unsigned short* __restrict__ A){
  const int t = threadIdx.x;
  for(int m = blockIdx.x; m < M_; m += gridDim.x){
    const int d = rank[m];
    if(d < 0) continue;
    const int id = ids[m];
    if(t < 192){
      const float4 v = *(const float4*)(table + (size_t)id*H_ + (t<<2));
      ushort4 o; o.x=f2bf(v.x); o.y=f2bf(v.y); o.z=f2bf(v.z); o.w=f2bf(v.w);
      *(ushort4*)(A + (size_t)d*H_ + (t<<2)) = o;
    }
  }
}

// ---- MFMA GEMM over per-batch-compacted rows: C = relu(A . Bw^T + bias) ----
// 128x128 tile, BK=32, 4 waves (2x2), 4x4 16x16x32 fragments/wave.
// Tiles align within a batch (512 % 128 == 0): skip tile if (m0&511) >= cnt[batch].
template<int KTOT, int NTOT>
__global__ __launch_bounds__(256) void k_gemm(
  const unsigned short* __restrict__ A, const unsigned short* __restrict__ Bw,
  const float* __restrict__ bias, const int* __restrict__ cnt,
  unsigned short* __restrict__ C)
{
  const int m0 = blockIdx.x << 7;
  if((m0 & (S_-1)) >= cnt[m0 >> 9]) return;
  __shared__ __align__(16) unsigned short As[128*32];
  __shared__ __align__(16) unsigned short Bs[128*32];
  const int tid = threadIdx.x;
  const int lane = tid & 63;
  const int wave = tid >> 6;
  const int wr = wave >> 1, wc = wave & 1;
  const int n0 = blockIdx.y << 7;

  const int f0 = tid, f1 = 256 + tid;
  const int r0 = f0 >> 2, s0 = ((f0 & 3) ^ ((f0 >> 3) & 3)) << 3;
  const int r1 = f1 >> 2, s1 = ((f1 & 3) ^ ((f1 >> 3) & 3)) << 3;
  const unsigned short* ga0 = A + (size_t)(m0 + r0)*KTOT + s0;
  const unsigned short* ga1 = A + (size_t)(m0 + r1)*KTOT + s1;
  const unsigned short* gb0 = Bw + (size_t)(n0 + r0)*KTOT + s0;
  const unsigned short* gb1 = Bw + (size_t)(n0 + r1)*KTOT + s1;
  unsigned short* la0 = As + (wave<<9);
  unsigned short* la1 = As + 2048 + (wave<<9);
  unsigned short* lb0 = Bs + (wave<<9);
  unsigned short* lb1 = Bs + 2048 + (wave<<9);

  f32x4 acc[4][4] = {};
  const int arow = (wr<<6) + (lane & 15);
  const int brow = (wc<<6) + (lane & 15);
  const int sl   = (((lane>>4) ^ ((lane>>1)&3)) << 3);

  for(int k0 = 0; k0 < KTOT; k0 += 32){
    gload_lds16(ga0 + k0, la0);
    gload_lds16(ga1 + k0, la1);
    gload_lds16(gb0 + k0, lb0);
    gload_lds16(gb1 + k0, lb1);
    __syncthreads();
    bf16x8 a[4], b[4];
    #pragma unroll
    for(int m=0;m<4;m++) a[m] = *(const bf16x8*)(As + (arow + (m<<4))*32 + sl);
    #pragma unroll
    for(int n=0;n<4;n++) b[n] = *(const bf16x8*)(Bs + (brow + (n<<4))*32 + sl);
    #pragma unroll
    for(int m=0;m<4;m++)
      #pragma unroll
      for(int n=0;n<4;n++)
        acc[m][n] = __builtin_amdgcn_mfma_f32_16x16x32_bf16(a[m], b[n], acc[m][n], 0,0,0);
    __syncthreads();
  }

  const int crow0 = (lane>>4) << 2;
  const int ccol  = lane & 15;
  float bia[4];
  #pragma unroll
  for(int n=0;n<4;n++) bia[n] = bias[n0 + (wc<<6) + (n<<4) + ccol];
  #pragma unroll
  for(int m=0;m<4;m++){
    const int gr0 = m0 + (wr<<6) + (m<<4) + crow0;
    #pragma unroll
    for(int j=0;j<4;j++){
      const size_t rbase = (size_t)(gr0 + j) * NTOT;
      #pragma unroll
      for(int n=0;n<4;n++){
        float v = acc[m][n][j] + bia[n];
        v = fmaxf(v, 0.f);
        C[rbase + n0 + (wc<<6) + (n<<4) + ccol] = f2bf(v);
      }
    }
  }
}

// ---- K5: compacted scores, scattered to full score array via perm ----
__global__ __launch_bounds__(256) void k_score(
  const unsigned short* __restrict__ A, const unsigned short* __restrict__ Bw,
  const float* __restrict__ ba1p, const float* __restrict__ Wa2p, const float* __restrict__ ba2,
  const int* __restrict__ perm, const int* __restrict__ cnt,
  float* __restrict__ scoresF)
{
  const int m0 = blockIdx.x << 7;
  const int scnt = cnt[m0 >> 9];
  const int mbase = m0 & (S_-1);
  if(mbase >= scnt) return;
  __shared__ __align__(16) unsigned short As[128*32];
  __shared__ __align__(16) unsigned short Bs[128*32];
  __shared__ float sums[128][2];
  __shared__ int sperm[128];
  const int tid = threadIdx.x;
  const int lane = tid & 63;
  const int wave = tid >> 6;
  const int wr = wave >> 1, wc = wave & 1;
  if(tid < 128) sperm[tid] = (mbase + tid < scnt) ? perm[m0 + tid] : 0;

  const int f0 = tid, f1 = 256 + tid;
  const int r0 = f0 >> 2, s0 = ((f0 & 3) ^ ((f0 >> 3) & 3)) << 3;
  const int r1 = f1 >> 2, s1 = ((f1 & 3) ^ ((f1 >> 3) & 3)) << 3;
  const unsigned short* ga0 = A + (size_t)(m0 + r0)*H_ + s0;
  const unsigned short* ga1 = A + (size_t)(m0 + r1)*H_ + s1;
  const unsigned short* gb0 = Bw + (size_t)r0*H_ + s0;
  const unsigned short* gb1 = Bw + (size_t)r1*H_ + s1;
  unsigned short* la0 = As + (wave<<9);
  unsigned short* la1 = As + 2048 + (wave<<9);
  unsigned short* lb0 = Bs + (wave<<9);
  unsigned short* lb1 = Bs + 2048 + (wave<<9);

  f32x4 acc[4][4] = {};
  const int arow = (wr<<6) + (lane & 15);
  const int brow = (wc<<6) + (lane & 15);
  const int sl   = (((lane>>4) ^ ((lane>>1)&3)) << 3);

  for(int k0 = 0; k0 < H_; k0 += 32){
    gload_lds16(ga0 + k0, la0);
    gload_lds16(ga1 + k0, la1);
    gload_lds16(gb0 + k0, lb0);
    gload_lds16(gb1 + k0, lb1);
    __syncthreads();
    bf16x8 a[4], b[4];
    #pragma unroll
    for(int m=0;m<4;m++) a[m] = *(const bf16x8*)(As + (arow + (m<<4))*32 + sl);
    #pragma unroll
    for(int n=0;n<4;n++) b[n] = *(const bf16x8*)(Bs + (brow + (n<<4))*32 + sl);
    #pragma unroll
    for(int m=0;m<4;m++)
      #pragma unroll
      for(int n=0;n<4;n++)
        acc[m][n] = __builtin_amdgcn_mfma_f32_16x16x32_bf16(a[m], b[n], acc[m][n], 0,0,0);
    __syncthreads();
  }

  float psum[4][4] = {};
  #pragma unroll
  for(int n=0;n<4;n++){
    const int c = (wc<<6) + (n<<4) + (lane & 15);
    const float w2 = Wa2p[c], bb = ba1p[c];
    #pragma unroll
    for(int m=0;m<4;m++)
      #pragma unroll
      for(int j=0;j<4;j++)
        psum[m][j] = fmaf(tanhf(acc[m][n][j] + bb), w2, psum[m][j]);
  }
  #pragma unroll
  for(int msk=1; msk<16; msk<<=1)
    #pragma unroll
    for(int m=0;m<4;m++)
      #pragma unroll
      for(int j=0;j<4;j++)
        psum[m][j] += __shfl_xor(psum[m][j], msk, 64);
  if((lane & 15) == 0){
    #pragma unroll
    for(int m=0;m<4;m++)
      #pragma unroll
      for(int j=0;j<4;j++)
        sums[(wr<<6) + (m<<4) + ((lane>>4)<<2) + j][wc] = psum[m][j];
  }
  __syncthreads();
  if(tid < 128 && (mbase + tid) < scnt)
    scoresF[sperm[tid]] = sums[tid][0] + sums[tid][1] + ba2[0];
}

// ---- K6: per-batch softmax; masked rows use constant score c0 ----
__global__ __launch_bounds__(256) void k_softmax(const float* __restrict__ scoresF,
  const float* __restrict__ maskf, const float* __restrict__ Wa2,
  const float* __restrict__ ba1, const float* __restrict__ ba2,
  float* __restrict__ attn){
  __shared__ float red[256];
  const int b = blockIdx.x, tid = threadIdx.x;
  red[tid] = (tid < 100) ? Wa2[tid]*tanhf(ba1[tid]) : 0.f;
  __syncthreads();
  for(int st=128; st>0; st>>=1){ if(tid<st) red[tid]+=red[tid+st]; __syncthreads(); }
  const float c0 = red[0] + ba2[0];
  __syncthreads();
  const int m1 = b*S_ + tid, m2 = m1 + 256;
  const float s1 = (tid==0) ? -1e30f : (maskf[m1] > 0.5f ? scoresF[m1] : c0);
  const float s2 = (maskf[m2] > 0.5f ? scoresF[m2] : c0);
  red[tid] = fmaxf(s1, s2); __syncthreads();
  for(int st=128; st>0; st>>=1){ if(tid<st) red[tid]=fmaxf(red[tid], red[tid+st]); __syncthreads(); }
  const float mx = red[0]; __syncthreads();
  const float e1 = (tid==0) ? 0.f : __expf(s1-mx);
  const float e2 = __expf(s2-mx);
  red[tid] = e1+e2; __syncthreads();
  for(int st=128; st>0; st>>=1){ if(tid<st) red[tid]+=red[tid+st]; __syncthreads(); }
  const float inv = 1.f/red[0];
  attn[m1] = e1*inv;
  attn[m2] = e2*inv;
}

// ---- K7: partial[b][ch][h] over batch b's compacted segment ----
__global__ __launch_bounds__(256) void k_partial(const unsigned short* __restrict__ wh,
  const float* __restrict__ attn, const int* __restrict__ perm, const int* __restrict__ cnt,
  float* __restrict__ partial){
  const int b = blockIdx.x >> 3, ch = blockIdx.x & 7, tid = threadIdx.x;
  const int n = min(cnt[b] - (ch<<6), 64);
  float* pp = partial + ((size_t)((b<<3)+ch))*H_;
  if(n <= 0){
    pp[tid] = 0.f; pp[tid+256] = 0.f; pp[tid+512] = 0.f;
    return;
  }
  const int j0 = b*S_ + (ch<<6);
  __shared__ float wts[64];
  if(tid < 64) wts[tid] = (tid < n) ? attn[perm[j0+tid]] : 0.f;
  __syncthreads();
  float a0=0.f, a1=0.f, a2=0.f;
  for(int t=0;t<n;t++){
    const float wv = wts[t];
    const size_t base = ((size_t)(j0+t))*H_;
    a0 = fmaf(wv, bf2f(wh[base + tid      ]), a0);
    a1 = fmaf(wv, bf2f(wh[base + tid + 256]), a1);
    a2 = fmaf(wv, bf2f(wh[base + tid + 512]), a2);
  }
  pp[tid] = a0; pp[tid+256] = a1; pp[tid+512] = a2;
}

// ---- K8: predicts[b] = [hiddens[b,0,:], cls_k[b,:]] @ Wl^T + bl ----
__global__ __launch_bounds__(256) void k_predict(const float* __restrict__ hiddens,
  const float* __restrict__ partial, const float* __restrict__ Wl, const float* __restrict__ bl,
  float* __restrict__ out){
  __shared__ float ck[768];
  __shared__ float red[256];
  const int b = blockIdx.x, tid = threadIdx.x;
  #pragma unroll
  for(int r=0;r<3;r++){
    const int h = tid + (r<<8);
    float s=0.f;
    for(int c=0;c<8;c++) s += partial[((size_t)((b<<3)+c))*H_ + h];
    ck[h]=s;
  }
  __syncthreads();
  const float* hid = hiddens + (size_t)b * S_ * H_;
  for(int c=0;c<3;c++){
    float p=0.f;
    #pragma unroll
    for(int r=0;r<3;r++){
      const int h = tid + (r<<8);
      p = fmaf(hid[h], Wl[c*1536 + h], p);
      p = fmaf(ck[h],  Wl[c*1536 + 768 + h], p);
    }
    red[tid]=p; __syncthreads();
    for(int st=128; st>0; st>>=1){ if(tid<st) red[tid]+=red[tid+st]; __syncthreads(); }
    if(tid==0) out[b*3+c] = red[0] + bl[c];
    __syncthreads();
  }
}

extern "C" void kernel_launch(void* const* d_in, const int* in_sizes, int n_in,
                              void* d_out, int out_size, void* d_ws, size_t ws_size,
                              hipStream_t stream)
{
  const float* hiddens = (const float*)d_in[0];
  const int*   ids     = (const int*)d_in[1];
  const void*  in_tab  = d_in[2];
  const float* table   = (const float*)d_in[3];
  const float* W1      = (const float*)d_in[4];
  const float* b1      = (const float*)d_in[5];
  const float* W2      = (const float*)d_in[6];
  const float* b2      = (const float*)d_in[7];
  const float* Wa1     = (const float*)d_in[8];
  const float* ba1     = (const float*)d_in[9];
  const float* Wa2     = (const float*)d_in[10];
  const float* ba2     = (const float*)d_in[11];
  const float* Wl      = (const float*)d_in[12];
  const float* bl      = (const float*)d_in[13];
  float* out = (float*)d_out;

  char* w = (char*)d_ws;
  unsigned short* Abf   = (unsigned short*)w;                // 25165824 B (aliased by wh)
  unsigned short* wh    = Abf;                               // alias: A dead after mlp1
  unsigned short* x     = (unsigned short*)(w + 25165824);   // 16777216
  unsigned short* W1bf  = (unsigned short*)(w + 41943040);   // 786432
  unsigned short* W2bf  = (unsigned short*)(w + 42729472);   // 786432
  unsigned short* Wa1bf = (unsigned short*)(w + 43515904);   // 196608
  float* Wa2p    = (float*)(w + 43712512);                   // 512
  float* ba1p    = (float*)(w + 43713024);                   // 512
  float* maskf   = (float*)(w + 43713536);                   // 65536
  float* scoresF = (float*)(w + 43779072);                   // 65536
  float* attn    = (float*)(w + 43844608);                   // 65536
  float* partial = (float*)(w + 43910144);                   // 786432
  int*   perm    = (int*)  (w + 44696576);                   // 65536
  int*   rank    = (int*)  (w + 44762112);                   // 65536
  int*   cnt     = (int*)  (w + 44827648);                   // 128

  hipLaunchKernelGGL(k_mask_scan, dim3(32), dim3(256), 0, stream, in_tab, ids, maskf, rank, perm, cnt);
  hipLaunchKernelGGL(k_prepw,  dim3(768),  dim3(256), 0, stream, W1, W2, Wa1, Wa2, ba1, W1bf, W2bf, Wa1bf, Wa2p, ba1p);
  hipLaunchKernelGGL(k_gather, dim3(2048), dim3(256), 0, stream, table, ids, rank, Abf);
  hipLaunchKernelGGL((k_gemm<H_, N1_>), dim3(128, 4), dim3(256), 0, stream, Abf, W1bf, b1, cnt, x);
  hipLaunchKernelGGL((k_gemm<N1_, H_>), dim3(128, 6), dim3(256), 0, stream, x, W2bf, b2, cnt, wh);
  hipLaunchKernelGGL(k_score,   dim3(128), dim3(256), 0, stream, wh, Wa1bf, ba1p, Wa2p, ba2, perm, cnt, scoresF);
  hipLaunchKernelGGL(k_softmax, dim3(32),  dim3(256), 0, stream, scoresF, maskf, Wa2, ba1, ba2, attn);
  hipLaunchKernelGGL(k_partial, dim3(256), dim3(256), 0, stream, wh, attn, perm, cnt, partial);
  hipLaunchKernelGGL(k_predict, dim3(32),  dim3(256), 0, stream, hiddens, partial, Wl, bl, out);
}